// Round 2
// baseline (339.338 us; speedup 1.0000x reference)
//
#include <hip/hip_runtime.h>

typedef __bf16 bf16x8 __attribute__((ext_vector_type(8)));
typedef float f32x4 __attribute__((ext_vector_type(4)));

#define T_SEQ 30
#define NIN 26
#define XPITCH 780  // T_SEQ * NIN

// wbuf layout (floats): W_ih[0..1871], W_hh[1872..3599], b_ih[3600..3671],
// b_hh[3672..3743], fc1_w[3744..3935], fc1_b[3936..3943], fc2_w[3944..3975], fc2_b[3976..3979]
#define W_IH 0
#define W_HH 1872
#define B_IH 3600
#define B_HH 3672
#define FC1W 3744
#define FC1B 3936
#define FC2W 3944
#define FC2B 3976

__device__ __forceinline__ float fast_sigmoid(float x) {
    return __builtin_amdgcn_rcpf(1.f + __expf(-x));
}
__device__ __forceinline__ float fast_tanh(float x) {
    // 2*sigmoid(2x)-1 ; graceful at saturation (exp->inf => -1, exp->0 => +1)
    return 2.f * __builtin_amdgcn_rcpf(1.f + __expf(-2.f * x)) - 1.f;
}

__global__ __launch_bounds__(256) void gru_kernel(
    const float* __restrict__ x, const float* __restrict__ W_ih,
    const float* __restrict__ W_hh, const float* __restrict__ b_ih,
    const float* __restrict__ b_hh, const float* __restrict__ fc1_w,
    const float* __restrict__ fc1_b, const float* __restrict__ fc2_w,
    const float* __restrict__ fc2_b, float* __restrict__ out)
{
    __shared__ float wbuf[3980];
    // chunk-major [4 kchunks][64 rows][8 elems] bf16 => b128 frag reads are cheap
    __shared__ __attribute__((aligned(16))) __bf16 x_lds[2048];
    __shared__ __attribute__((aligned(16))) __bf16 h_lds[2048];

    const int tid = threadIdx.x;
    const int lane = tid & 63;
    const int w16 = (tid >> 6) << 4;   // wave id * 16 (batch-row base within block)
    const int m = lane & 15;           // A row / B col within tile
    const int kg = lane >> 4;          // k-chunk group
    const int b0 = blockIdx.x << 6;    // 64 batch rows per block

    // ---- stage weights to LDS ----
    for (int i = tid; i < 1872; i += 256) wbuf[W_IH + i] = W_ih[i];
    for (int i = tid; i < 1728; i += 256) wbuf[W_HH + i] = W_hh[i];
    if (tid < 72) wbuf[B_IH + tid] = b_ih[tid];
    else if (tid < 144) wbuf[B_IH + tid] = b_hh[tid - 72];
    if (tid < 192) wbuf[FC1W + tid] = fc1_w[tid];
    if (tid < 8)   wbuf[FC1B + tid] = fc1_b[tid];
    if (tid < 32)  wbuf[FC2W + tid] = fc2_w[tid];
    if (tid < 4)   wbuf[FC2B + tid] = fc2_b[tid];
    for (int i = tid; i < 2048; i += 256) h_lds[i] = (__bf16)0.f;  // h0 = 0, incl. k-pad
    __syncthreads();

    // ---- build loop-invariant B fragments + bias C-init fragments ----
    // padded N = 96: gate g' occupies cols 32g'..32g'+23 ; tile Tn covers cols 16Tn..16Tn+15
    bf16x8 bIh[6], bHh[6];
    f32x4 bX[6], bH[6];
    #pragma unroll
    for (int Tn = 0; Tn < 6; ++Tn) {
        const int np = Tn * 16 + m;
        const int gp = np >> 5;
        const int jh = np & 31;
        const bool vc = jh < 24;
        const int g = gp * 24 + jh;    // original weight row (valid iff vc)
        #pragma unroll
        for (int e = 0; e < 8; ++e) {
            const int k = kg * 8 + e;
            const float vi = (vc && k < 26) ? wbuf[W_IH + g * 26 + k] : 0.f;
            const float vh = (vc && k < 24) ? wbuf[W_HH + g * 24 + k] : 0.f;
            bIh[Tn][e] = (__bf16)vi;
            bHh[Tn][e] = (__bf16)vh;
        }
        const float bx = vc ? wbuf[B_IH + g] : 0.f;
        const float bh = vc ? wbuf[B_HH + g] : 0.f;
        f32x4 vbx = {bx, bx, bx, bx};
        f32x4 vbh = {bh, bh, bh, bh};
        bX[Tn] = vbx;
        bH[Tn] = vbh;
    }

    // ---- x staging: thread owns (row = tid>>2, chunk = tid&3) -> 8 floats -> one ds_write_b128 ----
    const int srow = tid >> 2, sch = tid & 3;
    const float* xsrc = x + (size_t)(b0 + srow) * XPITCH + sch * 8;

    {   // t = 0
        float st[8];
        #pragma unroll
        for (int e = 0; e < 8; ++e) {
            const int c = sch * 8 + e;
            st[e] = (c < NIN) ? xsrc[e] : 0.f;
        }
        bf16x8 wv;
        #pragma unroll
        for (int e = 0; e < 8; ++e) wv[e] = (__bf16)st[e];
        *(bf16x8*)&x_lds[sch * 512 + srow * 8] = wv;
    }
    __syncthreads();

    f32x4 hc0 = {0.f, 0.f, 0.f, 0.f}, hc1 = {0.f, 0.f, 0.f, 0.f};
    const int fragoff = kg * 512 + (w16 + m) * 8;
    const int rowbase = w16 + kg * 4;   // C/D row = (lane>>4)*4 + reg

    #pragma unroll 1
    for (int t = 0; t < T_SEQ; ++t) {
        // issue next-timestep global loads early (latency hides under MFMA+gates)
        float nst[8];
        if (t < T_SEQ - 1) {
            const float* p = xsrc + (t + 1) * NIN;
            #pragma unroll
            for (int e = 0; e < 8; ++e) {
                const int c = sch * 8 + e;
                nst[e] = (c < NIN) ? p[e] : 0.f;
            }
        }

        const bf16x8 ax = *(const bf16x8*)&x_lds[fragoff];
        const bf16x8 ah = *(const bf16x8*)&h_lds[fragoff];

        f32x4 aX[6], aH[6];
        #pragma unroll
        for (int Tn = 0; Tn < 6; ++Tn)
            aX[Tn] = __builtin_amdgcn_mfma_f32_16x16x32_bf16(ax, bIh[Tn], bX[Tn], 0, 0, 0);
        #pragma unroll
        for (int Tn = 0; Tn < 6; ++Tn)
            aH[Tn] = __builtin_amdgcn_mfma_f32_16x16x32_bf16(ah, bHh[Tn], bH[Tn], 0, 0, 0);

        // gates: tiles {tp, 2+tp, 4+tp} hold r,z,n for the SAME (row, jh) per lane/reg
        #pragma unroll
        for (int tp = 0; tp < 2; ++tp) {
            f32x4& hc = tp ? hc1 : hc0;
            #pragma unroll
            for (int r = 0; r < 4; ++r) {
                const float rg = fast_sigmoid(aX[tp][r] + aH[tp][r]);
                const float zg = fast_sigmoid(aX[2 + tp][r] + aH[2 + tp][r]);
                const float ng = fast_tanh(aX[4 + tp][r] + rg * aH[4 + tp][r]);
                hc[r] = ng + zg * (hc[r] - ng);
            }
        }

        // write h back (wave-private rows; ordered vs next read by the barrier pair)
        #pragma unroll
        for (int r = 0; r < 4; ++r)
            h_lds[(m >> 3) * 512 + (rowbase + r) * 8 + (m & 7)] = (__bf16)hc0[r];
        if (m < 8) {
            #pragma unroll
            for (int r = 0; r < 4; ++r)
                h_lds[2 * 512 + (rowbase + r) * 8 + m] = (__bf16)hc1[r];
        }

        __syncthreads();   // everyone done reading x_lds
        if (t < T_SEQ - 1) {
            bf16x8 wv;
            #pragma unroll
            for (int e = 0; e < 8; ++e) wv[e] = (__bf16)nst[e];
            *(bf16x8*)&x_lds[sch * 512 + srow * 8] = wv;
        }
        __syncthreads();   // staging visible
    }

    // ---- epilogue: fc1 -> relu -> fc2 -> softmax, one lane per batch row ----
    if (lane < 16) {
        const int row = w16 + lane;
        float hv[24];
        #pragma unroll
        for (int j = 0; j < 24; ++j)
            hv[j] = (float)h_lds[(j >> 3) * 512 + row * 8 + (j & 7)];
        float lg[4] = {wbuf[FC2B], wbuf[FC2B + 1], wbuf[FC2B + 2], wbuf[FC2B + 3]};
        #pragma unroll
        for (int o = 0; o < 8; ++o) {
            float s = wbuf[FC1B + o];
            #pragma unroll
            for (int j = 0; j < 24; ++j) s += wbuf[FC1W + o * 24 + j] * hv[j];
            s = fmaxf(s, 0.f);
            #pragma unroll
            for (int c = 0; c < 4; ++c) lg[c] += wbuf[FC2W + c * 8 + o] * s;
        }
        const float mx = fmaxf(fmaxf(lg[0], lg[1]), fmaxf(lg[2], lg[3]));
        const float e0 = __expf(lg[0] - mx), e1 = __expf(lg[1] - mx);
        const float e2 = __expf(lg[2] - mx), e3 = __expf(lg[3] - mx);
        const float inv = __builtin_amdgcn_rcpf(e0 + e1 + e2 + e3);
        f32x4 pr = {e0 * inv, e1 * inv, e2 * inv, e3 * inv};
        *(f32x4*)&out[(size_t)(b0 + row) * 4] = pr;
    }
}

extern "C" void kernel_launch(void* const* d_in, const int* in_sizes, int n_in,
                              void* d_out, int out_size, void* d_ws, size_t ws_size,
                              hipStream_t stream) {
    const float* xx    = (const float*)d_in[0];
    const float* w_ih  = (const float*)d_in[1];
    const float* w_hh  = (const float*)d_in[2];
    const float* bih   = (const float*)d_in[3];
    const float* bhh   = (const float*)d_in[4];
    const float* f1w   = (const float*)d_in[5];
    const float* f1b   = (const float*)d_in[6];
    const float* f2w   = (const float*)d_in[7];
    const float* f2b   = (const float*)d_in[8];
    float* outp = (float*)d_out;

    dim3 grid(65536 / 64), block(256);
    gru_kernel<<<grid, block, 0, stream>>>(xx, w_ih, w_hh, bih, bhh, f1w, f1b, f2w, f2b, outp);
}

// Round 3
// 322.965 us; speedup vs baseline: 1.0507x; 1.0507x over previous
//
#include <hip/hip_runtime.h>

typedef __bf16 bf16x8 __attribute__((ext_vector_type(8)));
typedef float f32x4 __attribute__((ext_vector_type(4)));
typedef float f32x2 __attribute__((ext_vector_type(2)));

#define T_SEQ 30
#define NIN 26
#define XPITCH 780  // T_SEQ * NIN

// wbuf layout (floats): W_ih[0..1871], W_hh[1872..3599], b_ih[3600..3671],
// b_hh[3672..3743], fc1_w[3744..3935], fc1_b[3936..3943], fc2_w[3944..3975], fc2_b[3976..3979]
#define W_IH 0
#define W_HH 1872
#define B_IH 3600
#define B_HH 3672
#define FC1W 3744
#define FC1B 3936
#define FC2W 3944
#define FC2B 3976

__device__ __forceinline__ float fast_sigmoid(float x) {
    return __builtin_amdgcn_rcpf(1.f + __expf(-x));
}
__device__ __forceinline__ float fast_tanh(float x) {
    return 2.f * __builtin_amdgcn_rcpf(1.f + __expf(-2.f * x)) - 1.f;
}

__global__ __launch_bounds__(256, 4) void gru_kernel(
    const float* __restrict__ x, const float* __restrict__ W_ih,
    const float* __restrict__ W_hh, const float* __restrict__ b_ih,
    const float* __restrict__ b_hh, const float* __restrict__ fc1_w,
    const float* __restrict__ fc1_b, const float* __restrict__ fc2_w,
    const float* __restrict__ fc2_b, float* __restrict__ out)
{
    __shared__ float wbuf[3980];
    // per-wave h tile: [16 rows][32 cols] bf16, col-block XOR-swizzled by (row>>2)
    __shared__ __attribute__((aligned(16))) __bf16 hbuf[4 * 512];

    const int tid = threadIdx.x;
    const int lane = tid & 63;
    const int wid = tid >> 6;
    const int m = lane & 15;           // A row / C col within tile
    const int kg = lane >> 4;          // k-chunk group (A), row-block (C)
    const int w16 = wid << 4;
    const int b0 = blockIdx.x << 6;    // 64 batch rows per block

    // ---- stage weights to LDS (single barrier in the whole kernel) ----
    for (int i = tid; i < 1872; i += 256) wbuf[W_IH + i] = W_ih[i];
    for (int i = tid; i < 1728; i += 256) wbuf[W_HH + i] = W_hh[i];
    if (tid < 72) wbuf[B_IH + tid] = b_ih[tid];
    else if (tid < 144) wbuf[B_IH + tid] = b_hh[tid - 72];
    if (tid < 192) wbuf[FC1W + tid] = fc1_w[tid];
    if (tid < 8)   wbuf[FC1B + tid] = fc1_b[tid];
    if (tid < 32)  wbuf[FC2W + tid] = fc2_w[tid];
    if (tid < 4)   wbuf[FC2B + tid] = fc2_b[tid];
    for (int i = tid; i < 2048; i += 256) hbuf[i] = (__bf16)0.f;  // h0 = 0 incl. k-pad cols 24..31
    __syncthreads();

    // ---- loop-invariant B fragments + per-lane scalar biases ----
    // padded N = 96: gate g' at cols 32g'..32g'+23 ; tile Tn = cols 16Tn..16Tn+15
    bf16x8 bIh[6], bHh[6];
    float bxc[6], bhc[6];
    #pragma unroll
    for (int Tn = 0; Tn < 6; ++Tn) {
        const int np = Tn * 16 + m;
        const int gp = np >> 5;
        const int jh = np & 31;
        const bool vc = jh < 24;
        const int g = gp * 24 + jh;
        #pragma unroll
        for (int e = 0; e < 8; ++e) {
            const int k = kg * 8 + e;
            const float vi = (vc && k < 26) ? wbuf[W_IH + g * 26 + k] : 0.f;
            const float vh = (vc && k < 24) ? wbuf[W_HH + g * 24 + k] : 0.f;
            bIh[Tn][e] = (__bf16)vi;
            bHh[Tn][e] = (__bf16)vh;
        }
        bxc[Tn] = vc ? wbuf[B_IH + g] : 0.f;
        bhc[Tn] = vc ? wbuf[B_HH + g] : 0.f;
    }
    // combine r/z biases (tiles 0..3); n-gate (tiles 4,5) must stay split
    const float brz0 = bxc[0] + bhc[0], brz1 = bxc[1] + bhc[1];
    const float brz2 = bxc[2] + bhc[2], brz3 = bxc[3] + bhc[3];

    __bf16* hw = &hbuf[wid * 512];

    // ---- per-lane x pointer: row (b0+w16+m), k-chunk kg (kg==3 -> only k=24,25) ----
    const float* px = x + (size_t)(b0 + w16 + m) * XPITCH + ((kg < 3) ? kg * 8 : 24);
    const bool full = (kg < 3);

    f32x2 zero2 = {0.f, 0.f};
    f32x2 xc0, xc1, xc2, xc3;
    xc1 = zero2; xc2 = zero2; xc3 = zero2;
    xc0 = *(const f32x2*)px;
    if (full) {
        xc1 = *(const f32x2*)(px + 2);
        xc2 = *(const f32x2*)(px + 4);
        xc3 = *(const f32x2*)(px + 6);
    }

    f32x4 hc0 = {0.f, 0.f, 0.f, 0.f}, hc1 = {0.f, 0.f, 0.f, 0.f};
    const f32x4 z4 = {0.f, 0.f, 0.f, 0.f};

    // LDS offsets (elements). read: row m, col-block kg^(m>>2). write: rows kg*4+r.
    const int ra  = m * 32 + ((kg ^ (m >> 2)) << 3);
    const int wr0 = (kg * 4) * 32 + ((((m >> 3) ^ kg) & 3) << 3) + (m & 7);  // cols 0..15
    const int wr1 = (kg * 4) * 32 + (((2 ^ kg) & 3) << 3) + m;               // cols 16..23 (m<8)

    #pragma unroll 2
    for (int t = 0; t < T_SEQ; ++t) {
        // prefetch t+1 into regs (no barriers anywhere -> latency hides under compute)
        f32x2 xn0, xn1, xn2, xn3;
        xn0 = zero2; xn1 = zero2; xn2 = zero2; xn3 = zero2;
        if (t < T_SEQ - 1) {
            const float* p = px + (t + 1) * NIN;
            xn0 = *(const f32x2*)p;
            if (full) {
                xn1 = *(const f32x2*)(p + 2);
                xn2 = *(const f32x2*)(p + 4);
                xn3 = *(const f32x2*)(p + 6);
            }
        }

        bf16x8 ax;
        ax[0] = (__bf16)xc0.x; ax[1] = (__bf16)xc0.y;
        ax[2] = (__bf16)xc1.x; ax[3] = (__bf16)xc1.y;
        ax[4] = (__bf16)xc2.x; ax[5] = (__bf16)xc2.y;
        ax[6] = (__bf16)xc3.x; ax[7] = (__bf16)xc3.y;

        // h fragment (transposed view of last timestep's write; same-wave program order)
        const bf16x8 ah = *(const bf16x8*)&hw[ra];

        // ---- tp = 0 : tiles 0 (r), 2 (z), 4 (n) ----
        {
            f32x4 xr = __builtin_amdgcn_mfma_f32_16x16x32_bf16(ax, bIh[0], z4, 0, 0, 0);
            f32x4 hr = __builtin_amdgcn_mfma_f32_16x16x32_bf16(ah, bHh[0], z4, 0, 0, 0);
            f32x4 xz = __builtin_amdgcn_mfma_f32_16x16x32_bf16(ax, bIh[2], z4, 0, 0, 0);
            f32x4 hz = __builtin_amdgcn_mfma_f32_16x16x32_bf16(ah, bHh[2], z4, 0, 0, 0);
            f32x4 xn_ = __builtin_amdgcn_mfma_f32_16x16x32_bf16(ax, bIh[4], z4, 0, 0, 0);
            f32x4 hn = __builtin_amdgcn_mfma_f32_16x16x32_bf16(ah, bHh[4], z4, 0, 0, 0);
            #pragma unroll
            for (int r = 0; r < 4; ++r) {
                const float rg = fast_sigmoid(xr[r] + hr[r] + brz0);
                const float zg = fast_sigmoid(xz[r] + hz[r] + brz2);
                const float ng = fast_tanh(xn_[r] + bxc[4] + rg * (hn[r] + bhc[4]));
                hc0[r] = ng + zg * (hc0[r] - ng);
            }
            #pragma unroll
            for (int r = 0; r < 4; ++r)
                hw[wr0 + r * 32] = (__bf16)hc0[r];
        }

        // ---- tp = 1 : tiles 1 (r), 3 (z), 5 (n) ----
        {
            f32x4 xr = __builtin_amdgcn_mfma_f32_16x16x32_bf16(ax, bIh[1], z4, 0, 0, 0);
            f32x4 hr = __builtin_amdgcn_mfma_f32_16x16x32_bf16(ah, bHh[1], z4, 0, 0, 0);
            f32x4 xz = __builtin_amdgcn_mfma_f32_16x16x32_bf16(ax, bIh[3], z4, 0, 0, 0);
            f32x4 hz = __builtin_amdgcn_mfma_f32_16x16x32_bf16(ah, bHh[3], z4, 0, 0, 0);
            f32x4 xn_ = __builtin_amdgcn_mfma_f32_16x16x32_bf16(ax, bIh[5], z4, 0, 0, 0);
            f32x4 hn = __builtin_amdgcn_mfma_f32_16x16x32_bf16(ah, bHh[5], z4, 0, 0, 0);
            #pragma unroll
            for (int r = 0; r < 4; ++r) {
                const float rg = fast_sigmoid(xr[r] + hr[r] + brz1);
                const float zg = fast_sigmoid(xz[r] + hz[r] + brz3);
                const float ng = fast_tanh(xn_[r] + bxc[5] + rg * (hn[r] + bhc[5]));
                hc1[r] = ng + zg * (hc1[r] - ng);
            }
            if (m < 8) {
                #pragma unroll
                for (int r = 0; r < 4; ++r)
                    hw[wr1 + r * 32] = (__bf16)hc1[r];
            }
        }

        xc0 = xn0; xc1 = xn1; xc2 = xn2; xc3 = xn3;
    }

    // ---- epilogue: fc1 -> relu -> fc2 -> softmax, one lane per batch row ----
    if (lane < 16) {
        const int row = lane;
        float hv[24];
        #pragma unroll
        for (int j = 0; j < 24; ++j)
            hv[j] = (float)hw[row * 32 + ((((j >> 3) ^ (row >> 2)) & 3) << 3) + (j & 7)];
        float lg[4] = {wbuf[FC2B], wbuf[FC2B + 1], wbuf[FC2B + 2], wbuf[FC2B + 3]};
        #pragma unroll
        for (int o = 0; o < 8; ++o) {
            float s = wbuf[FC1B + o];
            #pragma unroll
            for (int j = 0; j < 24; ++j) s += wbuf[FC1W + o * 24 + j] * hv[j];
            s = fmaxf(s, 0.f);
            #pragma unroll
            for (int c = 0; c < 4; ++c) lg[c] += wbuf[FC2W + c * 8 + o] * s;
        }
        const float mx = fmaxf(fmaxf(lg[0], lg[1]), fmaxf(lg[2], lg[3]));
        const float e0 = __expf(lg[0] - mx), e1 = __expf(lg[1] - mx);
        const float e2 = __expf(lg[2] - mx), e3 = __expf(lg[3] - mx);
        const float inv = __builtin_amdgcn_rcpf(e0 + e1 + e2 + e3);
        f32x4 pr = {e0 * inv, e1 * inv, e2 * inv, e3 * inv};
        *(f32x4*)&out[(size_t)(b0 + w16 + row) * 4] = pr;
    }
}

extern "C" void kernel_launch(void* const* d_in, const int* in_sizes, int n_in,
                              void* d_out, int out_size, void* d_ws, size_t ws_size,
                              hipStream_t stream) {
    const float* xx    = (const float*)d_in[0];
    const float* w_ih  = (const float*)d_in[1];
    const float* w_hh  = (const float*)d_in[2];
    const float* bih   = (const float*)d_in[3];
    const float* bhh   = (const float*)d_in[4];
    const float* f1w   = (const float*)d_in[5];
    const float* f1b   = (const float*)d_in[6];
    const float* f2w   = (const float*)d_in[7];
    const float* f2b   = (const float*)d_in[8];
    float* outp = (float*)d_out;

    dim3 grid(65536 / 64), block(256);
    gru_kernel<<<grid, block, 0, stream>>>(xx, w_ih, w_hh, bih, bhh, f1w, f1b, f2w, f2b, outp);
}